// Round 8
// baseline (285.122 us; speedup 1.0000x reference)
//
#include <hip/hip_runtime.h>
#include <math.h>

#define SIM_T 100

// ---------------------------------------------------------------------------
// Transpose encW [out][in] -> encWT [in][out] so GEMM weight reads are k-major.
// ---------------------------------------------------------------------------
__global__ __launch_bounds__(256) void k_transpose256(
    const float* __restrict__ W, float* __restrict__ WT) {
  int k = blockIdx.x;
  int o = threadIdx.x;
  WT[k * 256 + o] = W[o * 256 + k];
}

// ---------------------------------------------------------------------------
// Pack x [8192 b][256 k] -> xp4 [64 k4][8192 b] (float4 = k4*4..k4*4+3).
// Write side coalesced; read side strided but one-shot (~32MB L2, ~2us).
// ---------------------------------------------------------------------------
__global__ __launch_bounds__(256) void k_packA(const float4* __restrict__ x4,
                                               float4* __restrict__ xp4) {
  int id = blockIdx.x * 256 + threadIdx.x;  // over 64*8192
  int k4 = id >> 13, b = id & 8191;
  xp4[id] = x4[(size_t)b * 64 + k4];
}

// ---------------------------------------------------------------------------
// GEMM: O[b][o] = epi( sum_k A[b][k] * WT[k][o] ), packed-transposed I/O.
// R8 structure ("TB"): lane = b -> A load xp4[k4*8192+b] perfectly coalesced
// (1 instr / 4k). W: wave-uniform float4 broadcast WT[k][obase..+3] (1 line
// per instr; VGPR-addressed via opaque `zero` so it stays on the TA path).
// Zero LDS, zero barriers; per-thread state = 4 acc -> ~56 VGPR -> 8 waves/
// SIMD (2048 blocks = 8 blocks/CU): latency hidden by TLP, unlike R6/R7's
// 2-wave SV. Per 4k-group: 5 VMEM + 16 fma (VALU-dominant).
// Output Op4[(obase>>2)*8192+b]: coalesced float4 store whose layout IS the
// next GEMM's A-format (self-propagating; also feeds k_sim directly).
// fmaf chain k-ascending per output == R1..R7 exact order (absmax 0).
// EPI 0: sigmoid(acc + bias)   EPI 1: acc * omd
// ---------------------------------------------------------------------------
template <int EPI>
__global__ __launch_bounds__(256, 8) void k_gemm_tb(
    const float4* __restrict__ Ap,   // [64 k4][8192 b]
    const float* __restrict__ WT,    // [256 k][256 o]
    const float* __restrict__ bias,  // encB (EPI=0) or unused
    float4* __restrict__ Op,         // [64 o4][8192 b]
    float omd, int zero) {
  const int t = threadIdx.x;
  const int lane = t & 63;
  const int wv = t >> 6;
  const int btile = blockIdx.x >> 4;  // 128 b-tiles of 64
  const int otile = blockIdx.x & 15;  // 16 o-tiles of 16
  const int b = btile * 64 + lane;
  const int obase = otile * 16 + wv * 4;
  const float4* Ab = Ap + b;
  const float* Wb = WT + obase + (lane & zero);  // VGPR addr, uniform value

  float acc0 = 0.f, acc1 = 0.f, acc2 = 0.f, acc3 = 0.f;

#pragma unroll 2
  for (int k4 = 0; k4 < 64; k4++) {
    float4 a = Ab[(size_t)k4 * 8192];
    float4 w0 = *(const float4*)(Wb + (k4 * 4 + 0) * 256);
    float4 w1 = *(const float4*)(Wb + (k4 * 4 + 1) * 256);
    float4 w2 = *(const float4*)(Wb + (k4 * 4 + 2) * 256);
    float4 w3 = *(const float4*)(Wb + (k4 * 4 + 3) * 256);
    // k ascending per acc: k4*4+0 .. k4*4+3
    acc0 = fmaf(a.x, w0.x, acc0);
    acc1 = fmaf(a.x, w0.y, acc1);
    acc2 = fmaf(a.x, w0.z, acc2);
    acc3 = fmaf(a.x, w0.w, acc3);
    acc0 = fmaf(a.y, w1.x, acc0);
    acc1 = fmaf(a.y, w1.y, acc1);
    acc2 = fmaf(a.y, w1.z, acc2);
    acc3 = fmaf(a.y, w1.w, acc3);
    acc0 = fmaf(a.z, w2.x, acc0);
    acc1 = fmaf(a.z, w2.y, acc1);
    acc2 = fmaf(a.z, w2.z, acc2);
    acc3 = fmaf(a.z, w2.w, acc3);
    acc0 = fmaf(a.w, w3.x, acc0);
    acc1 = fmaf(a.w, w3.y, acc1);
    acc2 = fmaf(a.w, w3.z, acc2);
    acc3 = fmaf(a.w, w3.w, acc3);
  }

  float4 o;
  if (EPI == 0) {
    float4 bv = *(const float4*)(bias + obase + (lane & zero));
    o.x = 1.f / (1.f + expf(-(acc0 + bv.x)));
    o.y = 1.f / (1.f + expf(-(acc1 + bv.y)));
    o.z = 1.f / (1.f + expf(-(acc2 + bv.z)));
    o.w = 1.f / (1.f + expf(-(acc3 + bv.w)));
  } else {
    o.x = __fmul_rn(acc0, omd);
    o.y = __fmul_rn(acc1, omd);
    o.z = __fmul_rn(acc2, omd);
    o.w = __fmul_rn(acc3, omd);
  }
  Op[(size_t)(obase >> 2) * 8192 + b] = o;  // coalesced
}

// ---------------------------------------------------------------------------
// Kernel: the 100-step LIF simulation. One wave == one batch row.
// QUAD layout (R8): lane l owns neurons {4l,4l+1,4l+2,4l+3} of layers 1/2
// and column l of layer 3. c input = one b128 from cp4[lane][row]. W2 rows
// are consumed RAW ((float4*)W2 + i*64 + lane == W2[i][4l..4l+3]) — no
// permutation kernel needed. Spike id from ballot m_q: 4*ctz + q.
// Layer-1 spike times bitwise-identical to prior rounds (same c bits, same
// update ops); layer-2/3 sum order is interleaved mod-4 instead of blocked —
// v2 sits far from threshold so 1e-7 reorder noise cannot flip spikes.
// ---------------------------------------------------------------------------
__global__ __launch_bounds__(256, 8) void k_sim(
    const float4* __restrict__ cp4,  // [64 o4][8192 b]
    const float* __restrict__ W2,    // [256][256] raw
    const float* __restrict__ W3,    // [256][64]
    float* __restrict__ out, float decay, float omd) {
  const int lane = threadIdx.x & 63;
  const int row = blockIdx.x * 4 + (threadIdx.x >> 6);
  float4 cv = cp4[(size_t)lane * 8192 + row];  // c for neurons 4l..4l+3
  const float c0 = cv.x, c1 = cv.y, c2 = cv.z, c3 = cv.w;
  float v10 = 0.f, v11 = 0.f, v12 = 0.f, v13 = 0.f;
  float v20 = 0.f, v21 = 0.f, v22 = 0.f, v23 = 0.f;
  float v3 = 0.f;
  int acc = 0;
  const float4* w2q = (const float4*)W2 + lane;  // w2q[r*64] = W2[r][4l..4l+3]
  const float* w3q = W3 + lane;

  for (int t = 0; t < SIM_T; t++) {
    // ---- layer 1 (constant input c) ----
    v10 = __fadd_rn(__fmul_rn(v10, decay), c0);
    bool f0 = v10 >= 1.f;
    unsigned long long m0 = __ballot(f0);
    v10 = f0 ? 0.f : v10;
    v11 = __fadd_rn(__fmul_rn(v11, decay), c1);
    bool f1 = v11 >= 1.f;
    unsigned long long m1 = __ballot(f1);
    v11 = f1 ? 0.f : v11;
    v12 = __fadd_rn(__fmul_rn(v12, decay), c2);
    bool f2 = v12 >= 1.f;
    unsigned long long m2 = __ballot(f2);
    v12 = f2 ? 0.f : v12;
    v13 = __fadd_rn(__fmul_rn(v13, decay), c3);
    bool f3 = v13 >= 1.f;
    unsigned long long m3 = __ballot(f3);
    v13 = f3 ? 0.f : v13;

    // ---- layer 2: sum W2 rows of spiking layer-1 neurons (id = 4*i+q) ----
    float s0 = 0.f, s1 = 0.f, s2 = 0.f, s3 = 0.f;
#define ACC2(mask, q)                             \
  {                                               \
    unsigned long long m = (mask);                \
    while (m) {                                   \
      int i = __builtin_ctzll(m);                 \
      m &= m - 1;                                 \
      float4 w = w2q[i * 256 + (q) * 64];         \
      s0 += w.x;                                  \
      s1 += w.y;                                  \
      s2 += w.z;                                  \
      s3 += w.w;                                  \
    }                                             \
  }
    ACC2(m0, 0)
    ACC2(m1, 1)
    ACC2(m2, 2)
    ACC2(m3, 3)

    v20 = __fadd_rn(__fmul_rn(v20, decay), __fmul_rn(s0, omd));
    bool g0 = v20 >= 1.f;
    unsigned long long n0 = __ballot(g0);
    v20 = g0 ? 0.f : v20;
    v21 = __fadd_rn(__fmul_rn(v21, decay), __fmul_rn(s1, omd));
    bool g1 = v21 >= 1.f;
    unsigned long long n1 = __ballot(g1);
    v21 = g1 ? 0.f : v21;
    v22 = __fadd_rn(__fmul_rn(v22, decay), __fmul_rn(s2, omd));
    bool g2 = v22 >= 1.f;
    unsigned long long n2 = __ballot(g2);
    v22 = g2 ? 0.f : v22;
    v23 = __fadd_rn(__fmul_rn(v23, decay), __fmul_rn(s3, omd));
    bool g3 = v23 >= 1.f;
    unsigned long long n3 = __ballot(g3);
    v23 = g3 ? 0.f : v23;

    // ---- layer 3 (usually no layer-2 spikes: uniform skip) ----
    float z = 0.f;
    if (n0 | n1 | n2 | n3) {
#define ACC3(mask, q)                             \
  {                                               \
    unsigned long long m = (mask);                \
    while (m) {                                   \
      int i = __builtin_ctzll(m);                 \
      m &= m - 1;                                 \
      z += w3q[(i * 4 + (q)) * 64];               \
    }                                             \
  }
      ACC3(n0, 0)
      ACC3(n1, 1)
      ACC3(n2, 2)
      ACC3(n3, 3)
    }
    v3 = __fadd_rn(__fmul_rn(v3, decay), __fmul_rn(z, omd));
    bool h = v3 >= 1.f;
    acc += h ? 1 : 0;
    v3 = h ? 0.f : v3;
  }
  out[(size_t)row * 64 + lane] = __fdiv_rn((float)acc, 100.f);
}

// ---------------------------------------------------------------------------
extern "C" void kernel_launch(void* const* d_in, const int* in_sizes, int n_in,
                              void* d_out, int out_size, void* d_ws,
                              size_t ws_size, hipStream_t stream) {
  const float* x = (const float*)d_in[0];     // [8192,256]
  const float* encW = (const float*)d_in[1];  // [256,256] (out,in)
  const float* encB = (const float*)d_in[2];  // [256]
  const float* W1 = (const float*)d_in[3];    // [256 k][256 o] already k-major
  const float* W2 = (const float*)d_in[4];    // [256,256]
  const float* W3 = (const float*)d_in[5];    // [256,64]
  float* out = (float*)d_out;                 // [8192,64]

  // workspace layout (floats): cp/xp alias [0..2M), rates_p [2M..4M),
  // encWT [4M..4M+64K). Total ~16.5 MB.
  float4* xp4 = (float4*)d_ws;                         // 8 MB (also cp)
  float4* rates_p4 = (float4*)((float*)d_ws + 2097152);  // 8 MB
  float* encWT = (float*)d_ws + 4194304;               // 256 KB

  const float decay = (float)exp((double)(-0.05f));
  const float omd = 1.0f - decay;
  const int zero = (int)(ws_size & 0);  // opaque runtime 0

  k_transpose256<<<256, 256, 0, stream>>>(encW, encWT);
  k_packA<<<2048, 256, 0, stream>>>((const float4*)x, xp4);
  k_gemm_tb<0><<<2048, 256, 0, stream>>>(xp4, encWT, encB, rates_p4, omd,
                                         zero);
  // GEMM2 writes cp into the xp buffer (xp dead after GEMM1 reads it... it is
  // read during GEMM1 only; GEMM2's A is rates_p4) -> safe aliasing.
  k_gemm_tb<1><<<2048, 256, 0, stream>>>(rates_p4, W1, encB, xp4, omd, zero);
  k_sim<<<2048, 256, 0, stream>>>((const float4*)xp4, W2, W3, out, decay, omd);
}

// Round 9
// 281.426 us; speedup vs baseline: 1.0131x; 1.0131x over previous
//
#include <hip/hip_runtime.h>
#include <math.h>

#define SIM_T 100

// ---------------------------------------------------------------------------
// Transpose encW [out][in] -> encWT [in][out] so GEMM weight reads are k-major.
// ---------------------------------------------------------------------------
__global__ __launch_bounds__(256) void k_transpose256(
    const float* __restrict__ W, float* __restrict__ WT) {
  int k = blockIdx.x;
  int o = threadIdx.x;
  WT[k * 256 + o] = W[o * 256 + k];
}

// ---------------------------------------------------------------------------
// Pack x [8192 b][256 k] -> xp4 [64 k4][8192 b] (float4 = k4*4..k4*4+3).
// ---------------------------------------------------------------------------
__global__ __launch_bounds__(256) void k_packA(const float4* __restrict__ x4,
                                               float4* __restrict__ xp4) {
  int id = blockIdx.x * 256 + threadIdx.x;  // over 64*8192
  int k4 = id >> 13, b = id & 8191;
  xp4[id] = x4[(size_t)b * 64 + k4];
}

// ---------------------------------------------------------------------------
// GEMM: O[b][o] = epi( sum_k A[b][k] * WT[k][o] ), packed-transposed I/O.
// R9 = R8 "TB" + XCD-locality swizzle. R8 post-mortem: VALUBusy 14%, FETCH
// 33MB = 4x A size -> A re-fetched from HBM by the 16 o-tile blocks of each
// b-tile (scattered across XCDs; ~900cy latency, latency-bound). Fix: HW
// round-robins blockIdx%8 across XCDs, so decompose btile = bid & 127,
// otile = bid >> 7: all 16 blocks sharing a b-tile are == btile (mod 8) ->
// SAME XCD, co-resident (2048 = 8/CU exactly). A-tile 64KB x 16/XCD = 1MB
// << 4MB L2 -> A hits L2 (~200cy), hidden by 8 waves/SIMD x 32 cyc/iter.
// Same map makes GEMM1's rates_p4 writes XCD-local for GEMM2's reads.
// Per 4k-group: 5 VMEM + 16 fma; 28 VGPR; zero LDS/barriers.
// fmaf chain k-ascending per output == R1..R8 exact order.
// EPI 0: sigmoid(acc + bias)   EPI 1: acc * omd
// ---------------------------------------------------------------------------
template <int EPI>
__global__ __launch_bounds__(256, 8) void k_gemm_tb(
    const float4* __restrict__ Ap,   // [64 k4][8192 b]
    const float* __restrict__ WT,    // [256 k][256 o]
    const float* __restrict__ bias,  // encB (EPI=0) or unused
    float4* __restrict__ Op,         // [64 o4][8192 b]
    float omd, int zero) {
  const int t = threadIdx.x;
  const int lane = t & 63;
  const int wv = t >> 6;
  const int btile = blockIdx.x & 127;  // XCD = btile % 8 (round-robin)
  const int otile = blockIdx.x >> 7;   // 16 o-tiles share this b-tile's L2
  const int b = btile * 64 + lane;
  const int obase = otile * 16 + wv * 4;
  const float4* Ab = Ap + b;
  const float* Wb = WT + obase + (lane & zero);  // VGPR addr, uniform value

  float acc0 = 0.f, acc1 = 0.f, acc2 = 0.f, acc3 = 0.f;

#pragma unroll 2
  for (int k4 = 0; k4 < 64; k4++) {
    float4 a = Ab[(size_t)k4 * 8192];
    float4 w0 = *(const float4*)(Wb + (k4 * 4 + 0) * 256);
    float4 w1 = *(const float4*)(Wb + (k4 * 4 + 1) * 256);
    float4 w2 = *(const float4*)(Wb + (k4 * 4 + 2) * 256);
    float4 w3 = *(const float4*)(Wb + (k4 * 4 + 3) * 256);
    // k ascending per acc: k4*4+0 .. k4*4+3
    acc0 = fmaf(a.x, w0.x, acc0);
    acc1 = fmaf(a.x, w0.y, acc1);
    acc2 = fmaf(a.x, w0.z, acc2);
    acc3 = fmaf(a.x, w0.w, acc3);
    acc0 = fmaf(a.y, w1.x, acc0);
    acc1 = fmaf(a.y, w1.y, acc1);
    acc2 = fmaf(a.y, w1.z, acc2);
    acc3 = fmaf(a.y, w1.w, acc3);
    acc0 = fmaf(a.z, w2.x, acc0);
    acc1 = fmaf(a.z, w2.y, acc1);
    acc2 = fmaf(a.z, w2.z, acc2);
    acc3 = fmaf(a.z, w2.w, acc3);
    acc0 = fmaf(a.w, w3.x, acc0);
    acc1 = fmaf(a.w, w3.y, acc1);
    acc2 = fmaf(a.w, w3.z, acc2);
    acc3 = fmaf(a.w, w3.w, acc3);
  }

  float4 o;
  if (EPI == 0) {
    float4 bv = *(const float4*)(bias + obase + (lane & zero));
    o.x = 1.f / (1.f + expf(-(acc0 + bv.x)));
    o.y = 1.f / (1.f + expf(-(acc1 + bv.y)));
    o.z = 1.f / (1.f + expf(-(acc2 + bv.z)));
    o.w = 1.f / (1.f + expf(-(acc3 + bv.w)));
  } else {
    o.x = __fmul_rn(acc0, omd);
    o.y = __fmul_rn(acc1, omd);
    o.z = __fmul_rn(acc2, omd);
    o.w = __fmul_rn(acc3, omd);
  }
  Op[(size_t)(obase >> 2) * 8192 + b] = o;  // coalesced
}

// ---------------------------------------------------------------------------
// Kernel: the 100-step LIF simulation. One wave == one batch row.
// QUAD layout: lane l owns neurons {4l..4l+3} of layers 1/2 and column l of
// layer 3; W2 rows consumed raw as float4. Spike sets via __ballot ->
// uniform scalar ctz loops.
// R9: membrane update fused to fmaf(v, decay, c) (1 instr vs mul+add; -9
// instrs/step of ~60). <=1ulp rounding change vs the 2-op chain; R8 proved
// output insensitivity to far larger reorderings (mod-4 sum interleave,
// absmax 0.0) — layer-2 membranes sit ~50 sigma below threshold.
// ---------------------------------------------------------------------------
__global__ __launch_bounds__(256, 8) void k_sim(
    const float4* __restrict__ cp4,  // [64 o4][8192 b]
    const float* __restrict__ W2,    // [256][256] raw
    const float* __restrict__ W3,    // [256][64]
    float* __restrict__ out, float decay, float omd) {
  const int lane = threadIdx.x & 63;
  const int row = blockIdx.x * 4 + (threadIdx.x >> 6);
  float4 cv = cp4[(size_t)lane * 8192 + row];  // c for neurons 4l..4l+3
  const float c0 = cv.x, c1 = cv.y, c2 = cv.z, c3 = cv.w;
  float v10 = 0.f, v11 = 0.f, v12 = 0.f, v13 = 0.f;
  float v20 = 0.f, v21 = 0.f, v22 = 0.f, v23 = 0.f;
  float v3 = 0.f;
  int acc = 0;
  const float4* w2q = (const float4*)W2 + lane;  // w2q[r*64] = W2[r][4l..4l+3]
  const float* w3q = W3 + lane;

  for (int t = 0; t < SIM_T; t++) {
    // ---- layer 1 (constant input c) ----
    v10 = fmaf(v10, decay, c0);
    bool f0 = v10 >= 1.f;
    unsigned long long m0 = __ballot(f0);
    v10 = f0 ? 0.f : v10;
    v11 = fmaf(v11, decay, c1);
    bool f1 = v11 >= 1.f;
    unsigned long long m1 = __ballot(f1);
    v11 = f1 ? 0.f : v11;
    v12 = fmaf(v12, decay, c2);
    bool f2 = v12 >= 1.f;
    unsigned long long m2 = __ballot(f2);
    v12 = f2 ? 0.f : v12;
    v13 = fmaf(v13, decay, c3);
    bool f3 = v13 >= 1.f;
    unsigned long long m3 = __ballot(f3);
    v13 = f3 ? 0.f : v13;

    // ---- layer 2: sum W2 rows of spiking layer-1 neurons (id = 4*i+q) ----
    float s0 = 0.f, s1 = 0.f, s2 = 0.f, s3 = 0.f;
#define ACC2(mask, q)                             \
  {                                               \
    unsigned long long m = (mask);                \
    while (m) {                                   \
      int i = __builtin_ctzll(m);                 \
      m &= m - 1;                                 \
      float4 w = w2q[i * 256 + (q) * 64];         \
      s0 += w.x;                                  \
      s1 += w.y;                                  \
      s2 += w.z;                                  \
      s3 += w.w;                                  \
    }                                             \
  }
    ACC2(m0, 0)
    ACC2(m1, 1)
    ACC2(m2, 2)
    ACC2(m3, 3)

    v20 = fmaf(v20, decay, __fmul_rn(s0, omd));
    bool g0 = v20 >= 1.f;
    unsigned long long n0 = __ballot(g0);
    v20 = g0 ? 0.f : v20;
    v21 = fmaf(v21, decay, __fmul_rn(s1, omd));
    bool g1 = v21 >= 1.f;
    unsigned long long n1 = __ballot(g1);
    v21 = g1 ? 0.f : v21;
    v22 = fmaf(v22, decay, __fmul_rn(s2, omd));
    bool g2 = v22 >= 1.f;
    unsigned long long n2 = __ballot(g2);
    v22 = g2 ? 0.f : v22;
    v23 = fmaf(v23, decay, __fmul_rn(s3, omd));
    bool g3 = v23 >= 1.f;
    unsigned long long n3 = __ballot(g3);
    v23 = g3 ? 0.f : v23;

    // ---- layer 3 (usually no layer-2 spikes: uniform skip) ----
    float z = 0.f;
    if (n0 | n1 | n2 | n3) {
#define ACC3(mask, q)                             \
  {                                               \
    unsigned long long m = (mask);                \
    while (m) {                                   \
      int i = __builtin_ctzll(m);                 \
      m &= m - 1;                                 \
      z += w3q[(i * 4 + (q)) * 64];               \
    }                                             \
  }
      ACC3(n0, 0)
      ACC3(n1, 1)
      ACC3(n2, 2)
      ACC3(n3, 3)
    }
    v3 = fmaf(v3, decay, __fmul_rn(z, omd));
    bool h = v3 >= 1.f;
    acc += h ? 1 : 0;
    v3 = h ? 0.f : v3;
  }
  out[(size_t)row * 64 + lane] = __fdiv_rn((float)acc, 100.f);
}

// ---------------------------------------------------------------------------
extern "C" void kernel_launch(void* const* d_in, const int* in_sizes, int n_in,
                              void* d_out, int out_size, void* d_ws,
                              size_t ws_size, hipStream_t stream) {
  const float* x = (const float*)d_in[0];     // [8192,256]
  const float* encW = (const float*)d_in[1];  // [256,256] (out,in)
  const float* encB = (const float*)d_in[2];  // [256]
  const float* W1 = (const float*)d_in[3];    // [256 k][256 o] already k-major
  const float* W2 = (const float*)d_in[4];    // [256,256]
  const float* W3 = (const float*)d_in[5];    // [256,64]
  float* out = (float*)d_out;                 // [8192,64]

  float4* xp4 = (float4*)d_ws;                           // 8 MB (also cp)
  float4* rates_p4 = (float4*)((float*)d_ws + 2097152);  // 8 MB
  float* encWT = (float*)d_ws + 4194304;                 // 256 KB

  const float decay = (float)exp((double)(-0.05f));
  const float omd = 1.0f - decay;
  const int zero = (int)(ws_size & 0);  // opaque runtime 0

  k_transpose256<<<256, 256, 0, stream>>>(encW, encWT);
  k_packA<<<2048, 256, 0, stream>>>((const float4*)x, xp4);
  k_gemm_tb<0><<<2048, 256, 0, stream>>>(xp4, encWT, encB, rates_p4, omd,
                                         zero);
  // GEMM2 writes cp into xp (xp only read by GEMM1) -> safe aliasing.
  k_gemm_tb<1><<<2048, 256, 0, stream>>>(rates_p4, W1, encB, xp4, omd, zero);
  k_sim<<<2048, 256, 0, stream>>>((const float4*)xp4, W2, W3, out, decay, omd);
}

// Round 10
// 181.117 us; speedup vs baseline: 1.5742x; 1.5538x over previous
//
#include <hip/hip_runtime.h>
#include <math.h>

#define SIM_T 100

// ---------------------------------------------------------------------------
// Prep (fused): blocks 0..255 transpose encW [o][k] -> encWT [k][o];
// blocks 256..2303 pack x [8192 b][256 k] -> xp4 [64 k4][8192 b].
// ---------------------------------------------------------------------------
__global__ __launch_bounds__(256) void k_prep(const float* __restrict__ encW,
                                              float* __restrict__ encWT,
                                              const float4* __restrict__ x4,
                                              float4* __restrict__ xp4) {
  int bid = blockIdx.x;
  int t = threadIdx.x;
  if (bid < 256) {
    encWT[bid * 256 + t] = encW[t * 256 + bid];
  } else {
    int id = (bid - 256) * 256 + t;  // over 64*8192
    int k4 = id >> 13, b = id & 8191;
    xp4[id] = x4[(size_t)b * 64 + k4];
  }
}

// ---------------------------------------------------------------------------
// GEMM: O[b][o] = epi( sum_k A[b][k] * WT[k][o] ), packed-transposed I/O.
// R10 "WS": R9 post-mortem showed the TA/L1 pipe is the bottleneck (FETCH
// dropped 33->5MB with zero dur change; VALUBusy 12%): per-lane 1KB loads
// cost ~16cy TA each and 32 waves/CU redundantly streamed A and W through TA.
// Here:
//   - A: lane = b, ONE coalesced float4 load per 4k-iter (only TA user).
//   - W: 16 cols/thread -> wave needs one contiguous 64B chunk WT[k][cb..+15]
//     at a readfirstlane-scalar address -> s_load_dwordx16 on the SMEM pipe
//     (off TA), SGPR operand straight into v_fma. (R4's s_load failure was
//     256 scattered 1KB-strided lines + uncoalesced A; these are contiguous.)
//   - Per 4k-iter: 1 TA instr + 4 scalar 64B loads + 64 fma instrs.
//     Per CU (8 waves): VALU 256cy/iter vs TA 128cy/iter -> VALU-bound,
//     floor ~7us/GEMM. 16 indep acc chains hide latency at 2 waves/SIMD.
// Grid 512 = 128 btiles x 4 colblocks; btile = bid&127 keeps same-btile
// blocks on one XCD (R9 map); 2 blocks/CU share one L1-resident A-tile.
// fmaf chain k-ascending per output == R1..R9 exact order (absmax 0).
// EPI 0: sigmoid(acc + bias)   EPI 1: acc * omd
// ---------------------------------------------------------------------------
template <int EPI>
__global__ __launch_bounds__(256, 2) void k_gemm_ws(
    const float4* __restrict__ Ap,   // [64 k4][8192 b]
    const float* __restrict__ WT,    // [256 k][256 o]
    const float* __restrict__ bias,  // encB (EPI=0) or unused
    float4* __restrict__ Op,         // [64 o4][8192 b]
    float omd) {
  const int lane = threadIdx.x & 63;
  const int wvS = __builtin_amdgcn_readfirstlane(threadIdx.x >> 6);
  const int btile = blockIdx.x & 127;  // XCD = btile % 8
  const int cb = blockIdx.x >> 7;      // 0..3
  const int b = btile * 64 + lane;
  const int colbase = cb * 64 + wvS * 16;  // fully scalar
  const float* wp = WT + colbase;          // SGPR base -> s_load stream
  const float4* Ab = Ap + b;

  float acc[16];
#pragma unroll
  for (int c = 0; c < 16; c++) acc[c] = 0.f;

#pragma unroll 4
  for (int k4 = 0; k4 < 64; k4++) {
    float4 a = Ab[(size_t)k4 * 8192];
    const float* af = &a.x;
#pragma unroll
    for (int kk = 0; kk < 4; kk++) {
      const float* wk = wp + (k4 * 4 + kk) * 256;  // scalar addr
#pragma unroll
      for (int c = 0; c < 16; c++) acc[c] = fmaf(af[kk], wk[c], acc[c]);
    }
  }

  // epilogue + 4 coalesced float4 stores (packed layout, self-propagating)
#pragma unroll
  for (int j = 0; j < 4; j++) {
    float4 o;
    float* of = &o.x;
    if (EPI == 0) {
#pragma unroll
      for (int q = 0; q < 4; q++) {
        float v = acc[j * 4 + q] + bias[colbase + j * 4 + q];
        of[q] = 1.f / (1.f + expf(-v));
      }
    } else {
#pragma unroll
      for (int q = 0; q < 4; q++) of[q] = __fmul_rn(acc[j * 4 + q], omd);
    }
    Op[(size_t)((colbase >> 2) + j) * 8192 + b] = o;
  }
}

// ---------------------------------------------------------------------------
// Kernel: the 100-step LIF simulation. One wave == one batch row.
// QUAD layout: lane l owns neurons {4l..4l+3} of layers 1/2 and column l of
// layer 3; W2 rows consumed raw as float4; membrane update fmaf-fused.
// Unchanged from R9 (absmax 0.0; ~75us, VALUBusy ~80%, VALU-bound).
// ---------------------------------------------------------------------------
__global__ __launch_bounds__(256, 8) void k_sim(
    const float4* __restrict__ cp4,  // [64 o4][8192 b]
    const float* __restrict__ W2,    // [256][256] raw
    const float* __restrict__ W3,    // [256][64]
    float* __restrict__ out, float decay, float omd) {
  const int lane = threadIdx.x & 63;
  const int row = blockIdx.x * 4 + (threadIdx.x >> 6);
  float4 cv = cp4[(size_t)lane * 8192 + row];  // c for neurons 4l..4l+3
  const float c0 = cv.x, c1 = cv.y, c2 = cv.z, c3 = cv.w;
  float v10 = 0.f, v11 = 0.f, v12 = 0.f, v13 = 0.f;
  float v20 = 0.f, v21 = 0.f, v22 = 0.f, v23 = 0.f;
  float v3 = 0.f;
  int acc = 0;
  const float4* w2q = (const float4*)W2 + lane;  // w2q[r*64] = W2[r][4l..4l+3]
  const float* w3q = W3 + lane;

  for (int t = 0; t < SIM_T; t++) {
    // ---- layer 1 (constant input c) ----
    v10 = fmaf(v10, decay, c0);
    bool f0 = v10 >= 1.f;
    unsigned long long m0 = __ballot(f0);
    v10 = f0 ? 0.f : v10;
    v11 = fmaf(v11, decay, c1);
    bool f1 = v11 >= 1.f;
    unsigned long long m1 = __ballot(f1);
    v11 = f1 ? 0.f : v11;
    v12 = fmaf(v12, decay, c2);
    bool f2 = v12 >= 1.f;
    unsigned long long m2 = __ballot(f2);
    v12 = f2 ? 0.f : v12;
    v13 = fmaf(v13, decay, c3);
    bool f3 = v13 >= 1.f;
    unsigned long long m3 = __ballot(f3);
    v13 = f3 ? 0.f : v13;

    // ---- layer 2: sum W2 rows of spiking layer-1 neurons (id = 4*i+q) ----
    float s0 = 0.f, s1 = 0.f, s2 = 0.f, s3 = 0.f;
#define ACC2(mask, q)                             \
  {                                               \
    unsigned long long m = (mask);                \
    while (m) {                                   \
      int i = __builtin_ctzll(m);                 \
      m &= m - 1;                                 \
      float4 w = w2q[i * 256 + (q) * 64];         \
      s0 += w.x;                                  \
      s1 += w.y;                                  \
      s2 += w.z;                                  \
      s3 += w.w;                                  \
    }                                             \
  }
    ACC2(m0, 0)
    ACC2(m1, 1)
    ACC2(m2, 2)
    ACC2(m3, 3)

    v20 = fmaf(v20, decay, __fmul_rn(s0, omd));
    bool g0 = v20 >= 1.f;
    unsigned long long n0 = __ballot(g0);
    v20 = g0 ? 0.f : v20;
    v21 = fmaf(v21, decay, __fmul_rn(s1, omd));
    bool g1 = v21 >= 1.f;
    unsigned long long n1 = __ballot(g1);
    v21 = g1 ? 0.f : v21;
    v22 = fmaf(v22, decay, __fmul_rn(s2, omd));
    bool g2 = v22 >= 1.f;
    unsigned long long n2 = __ballot(g2);
    v22 = g2 ? 0.f : v22;
    v23 = fmaf(v23, decay, __fmul_rn(s3, omd));
    bool g3 = v23 >= 1.f;
    unsigned long long n3 = __ballot(g3);
    v23 = g3 ? 0.f : v23;

    // ---- layer 3 (usually no layer-2 spikes: uniform skip) ----
    float z = 0.f;
    if (n0 | n1 | n2 | n3) {
#define ACC3(mask, q)                             \
  {                                               \
    unsigned long long m = (mask);                \
    while (m) {                                   \
      int i = __builtin_ctzll(m);                 \
      m &= m - 1;                                 \
      z += w3q[(i * 4 + (q)) * 64];               \
    }                                             \
  }
      ACC3(n0, 0)
      ACC3(n1, 1)
      ACC3(n2, 2)
      ACC3(n3, 3)
    }
    v3 = fmaf(v3, decay, __fmul_rn(z, omd));
    bool h = v3 >= 1.f;
    acc += h ? 1 : 0;
    v3 = h ? 0.f : v3;
  }
  out[(size_t)row * 64 + lane] = __fdiv_rn((float)acc, 100.f);
}

// ---------------------------------------------------------------------------
extern "C" void kernel_launch(void* const* d_in, const int* in_sizes, int n_in,
                              void* d_out, int out_size, void* d_ws,
                              size_t ws_size, hipStream_t stream) {
  const float* x = (const float*)d_in[0];     // [8192,256]
  const float* encW = (const float*)d_in[1];  // [256,256] (out,in)
  const float* encB = (const float*)d_in[2];  // [256]
  const float* W1 = (const float*)d_in[3];    // [256 k][256 o] already k-major
  const float* W2 = (const float*)d_in[4];    // [256,256]
  const float* W3 = (const float*)d_in[5];    // [256,64]
  float* out = (float*)d_out;                 // [8192,64]

  float4* xp4 = (float4*)d_ws;                           // 8 MB (also cp)
  float4* rates_p4 = (float4*)((float*)d_ws + 2097152);  // 8 MB
  float* encWT = (float*)d_ws + 4194304;                 // 256 KB

  const float decay = (float)exp((double)(-0.05f));
  const float omd = 1.0f - decay;

  k_prep<<<2304, 256, 0, stream>>>(encW, encWT, (const float4*)x, xp4);
  k_gemm_ws<0><<<512, 256, 0, stream>>>(xp4, encWT, encB, rates_p4, omd);
  // GEMM2 writes cp into xp (xp only read by GEMM1) -> safe aliasing.
  k_gemm_ws<1><<<512, 256, 0, stream>>>(rates_p4, W1, encB, xp4, omd);
  k_sim<<<2048, 256, 0, stream>>>((const float4*)xp4, W2, W3, out, decay, omd);
}

// Round 11
// 174.775 us; speedup vs baseline: 1.6314x; 1.0363x over previous
//
#include <hip/hip_runtime.h>
#include <math.h>

#define SIM_T 100

// ---------------------------------------------------------------------------
// Transpose encW [out][in] -> encWT [in][out] (256KB, one-shot, ~2us).
// ---------------------------------------------------------------------------
__global__ __launch_bounds__(256) void k_transpose256(
    const float* __restrict__ W, float* __restrict__ WT) {
  int k = blockIdx.x;
  int o = threadIdx.x;
  WT[k * 256 + o] = W[o * 256 + k];
}

// ---------------------------------------------------------------------------
// Pack x [8192 b][256 k] -> xp4 [64 k4][8192 b], LDS-tiled so BOTH global
// sides are coalesced (R10's k_packA read at 1KB stride = 4x line
// amplification). 512 blocks: tile = 64 b x 16 k4 float4 (16KB LDS, XOR
// swizzle -> conflict-free b128 both phases).
// ---------------------------------------------------------------------------
__global__ __launch_bounds__(256) void k_pack(const float4* __restrict__ x4,
                                              float4* __restrict__ xp4) {
  __shared__ float4 lds[64 * 16];  // 16KB
  const int t = threadIdx.x;
  const int btile = blockIdx.x >> 2;  // 128 b-tiles of 64
  const int k4t = blockIdx.x & 3;     // 4 k4-tiles of 16
#pragma unroll
  for (int i = 0; i < 4; i++) {
    int id = i * 256 + t;
    int bl = id >> 4, kl = id & 15;  // row bl, col kl (256B contiguous/16 ln)
    lds[bl * 16 + (kl ^ (bl & 15))] =
        x4[(size_t)(btile * 64 + bl) * 64 + k4t * 16 + kl];
  }
  __syncthreads();
#pragma unroll
  for (int i = 0; i < 4; i++) {
    int id = i * 256 + t;
    int kl = id >> 6, bl = id & 63;  // fixed k4 per wave, b = lane (1KB store)
    xp4[(size_t)(k4t * 16 + kl) * 8192 + btile * 64 + bl] =
        lds[bl * 16 + (kl ^ (bl & 15))];
  }
}

// ---------------------------------------------------------------------------
// GEMM: O[b][o] = epi( sum_k A[b][k] * WT[k][o] ), packed-transposed I/O.
// R11 "WS/8": R10's C=16 ran at 2 waves/SIMD (grid 512) and the OoO SMEM
// (s_load_dwordx16, lgkmcnt(0) drains, ~4 outstanding max at ~102 SGPR)
// left ~60% of SIMD cycles stalled. C=8 keeps the same FMA total but:
//   grid 1024 = 4 blocks/CU = 4 waves/SIMD (2x TLP), 32 SGPR in flight
//   per iter (2x prefetch depth), A still the only TA user (1 coalesced
//   float4/iter). Per 4k-iter: 1 TA + 4 s_load_dwordx8 + 32 fma.
// fmaf chain k-ascending per output == R1..R10 exact order (absmax 0).
// EPI 0: sigmoid(acc + bias)   EPI 1: acc * omd
// ---------------------------------------------------------------------------
template <int EPI>
__global__ __launch_bounds__(256, 4) void k_gemm_ws(
    const float4* __restrict__ Ap,   // [64 k4][8192 b]
    const float* __restrict__ WT,    // [256 k][256 o]
    const float* __restrict__ bias,  // encB (EPI=0) or unused
    float4* __restrict__ Op,         // [64 o4][8192 b]
    float omd) {
  const int lane = threadIdx.x & 63;
  const int wvS = __builtin_amdgcn_readfirstlane(threadIdx.x >> 6);
  const int btile = blockIdx.x & 127;  // XCD = btile % 8 (same-btile co-XCD)
  const int cb = blockIdx.x >> 7;      // 0..7 col-blocks of 32
  const int b = btile * 64 + lane;
  const int colbase = cb * 32 + wvS * 8;  // fully scalar
  const float* wp = WT + colbase;         // SGPR base -> s_load stream
  const float4* Ab = Ap + b;

  float acc[8];
#pragma unroll
  for (int c = 0; c < 8; c++) acc[c] = 0.f;

#pragma unroll 4
  for (int k4 = 0; k4 < 64; k4++) {
    float4 a = Ab[(size_t)k4 * 8192];
    const float* af = &a.x;
#pragma unroll
    for (int kk = 0; kk < 4; kk++) {
      const float* wk = wp + (k4 * 4 + kk) * 256;  // scalar addr
#pragma unroll
      for (int c = 0; c < 8; c++) acc[c] = fmaf(af[kk], wk[c], acc[c]);
    }
  }

  // epilogue + 2 coalesced float4 stores (packed layout, self-propagating)
#pragma unroll
  for (int j = 0; j < 2; j++) {
    float4 o;
    float* of = &o.x;
    if (EPI == 0) {
#pragma unroll
      for (int q = 0; q < 4; q++) {
        float v = acc[j * 4 + q] + bias[colbase + j * 4 + q];
        of[q] = 1.f / (1.f + expf(-v));
      }
    } else {
#pragma unroll
      for (int q = 0; q < 4; q++) of[q] = __fmul_rn(acc[j * 4 + q], omd);
    }
    Op[(size_t)((colbase >> 2) + j) * 8192 + b] = o;
  }
}

// ---------------------------------------------------------------------------
// Kernel: the 100-step LIF simulation. One wave == one batch row.
// QUAD layout: lane l owns neurons {4l..4l+3} of layers 1/2 and column l of
// layer 3; W2 rows consumed raw as float4; membrane update fmaf-fused.
// Unchanged from R10 (absmax 0.0; 69.6us, VALUBusy 76%, VALU-bound).
// ---------------------------------------------------------------------------
__global__ __launch_bounds__(256, 8) void k_sim(
    const float4* __restrict__ cp4,  // [64 o4][8192 b]
    const float* __restrict__ W2,    // [256][256] raw
    const float* __restrict__ W3,    // [256][64]
    float* __restrict__ out, float decay, float omd) {
  const int lane = threadIdx.x & 63;
  const int row = blockIdx.x * 4 + (threadIdx.x >> 6);
  float4 cv = cp4[(size_t)lane * 8192 + row];  // c for neurons 4l..4l+3
  const float c0 = cv.x, c1 = cv.y, c2 = cv.z, c3 = cv.w;
  float v10 = 0.f, v11 = 0.f, v12 = 0.f, v13 = 0.f;
  float v20 = 0.f, v21 = 0.f, v22 = 0.f, v23 = 0.f;
  float v3 = 0.f;
  int acc = 0;
  const float4* w2q = (const float4*)W2 + lane;  // w2q[r*64] = W2[r][4l..4l+3]
  const float* w3q = W3 + lane;

  for (int t = 0; t < SIM_T; t++) {
    // ---- layer 1 (constant input c) ----
    v10 = fmaf(v10, decay, c0);
    bool f0 = v10 >= 1.f;
    unsigned long long m0 = __ballot(f0);
    v10 = f0 ? 0.f : v10;
    v11 = fmaf(v11, decay, c1);
    bool f1 = v11 >= 1.f;
    unsigned long long m1 = __ballot(f1);
    v11 = f1 ? 0.f : v11;
    v12 = fmaf(v12, decay, c2);
    bool f2 = v12 >= 1.f;
    unsigned long long m2 = __ballot(f2);
    v12 = f2 ? 0.f : v12;
    v13 = fmaf(v13, decay, c3);
    bool f3 = v13 >= 1.f;
    unsigned long long m3 = __ballot(f3);
    v13 = f3 ? 0.f : v13;

    // ---- layer 2: sum W2 rows of spiking layer-1 neurons (id = 4*i+q) ----
    float s0 = 0.f, s1 = 0.f, s2 = 0.f, s3 = 0.f;
#define ACC2(mask, q)                             \
  {                                               \
    unsigned long long m = (mask);                \
    while (m) {                                   \
      int i = __builtin_ctzll(m);                 \
      m &= m - 1;                                 \
      float4 w = w2q[i * 256 + (q) * 64];         \
      s0 += w.x;                                  \
      s1 += w.y;                                  \
      s2 += w.z;                                  \
      s3 += w.w;                                  \
    }                                             \
  }
    ACC2(m0, 0)
    ACC2(m1, 1)
    ACC2(m2, 2)
    ACC2(m3, 3)

    v20 = fmaf(v20, decay, __fmul_rn(s0, omd));
    bool g0 = v20 >= 1.f;
    unsigned long long n0 = __ballot(g0);
    v20 = g0 ? 0.f : v20;
    v21 = fmaf(v21, decay, __fmul_rn(s1, omd));
    bool g1 = v21 >= 1.f;
    unsigned long long n1 = __ballot(g1);
    v21 = g1 ? 0.f : v21;
    v22 = fmaf(v22, decay, __fmul_rn(s2, omd));
    bool g2 = v22 >= 1.f;
    unsigned long long n2 = __ballot(g2);
    v22 = g2 ? 0.f : v22;
    v23 = fmaf(v23, decay, __fmul_rn(s3, omd));
    bool g3 = v23 >= 1.f;
    unsigned long long n3 = __ballot(g3);
    v23 = g3 ? 0.f : v23;

    // ---- layer 3 (usually no layer-2 spikes: uniform skip) ----
    float z = 0.f;
    if (n0 | n1 | n2 | n3) {
#define ACC3(mask, q)                             \
  {                                               \
    unsigned long long m = (mask);                \
    while (m) {                                   \
      int i = __builtin_ctzll(m);                 \
      m &= m - 1;                                 \
      z += w3q[(i * 4 + (q)) * 64];               \
    }                                             \
  }
      ACC3(n0, 0)
      ACC3(n1, 1)
      ACC3(n2, 2)
      ACC3(n3, 3)
    }
    v3 = fmaf(v3, decay, __fmul_rn(z, omd));
    bool h = v3 >= 1.f;
    acc += h ? 1 : 0;
    v3 = h ? 0.f : v3;
  }
  out[(size_t)row * 64 + lane] = __fdiv_rn((float)acc, 100.f);
}

// ---------------------------------------------------------------------------
extern "C" void kernel_launch(void* const* d_in, const int* in_sizes, int n_in,
                              void* d_out, int out_size, void* d_ws,
                              size_t ws_size, hipStream_t stream) {
  const float* x = (const float*)d_in[0];     // [8192,256]
  const float* encW = (const float*)d_in[1];  // [256,256] (out,in)
  const float* encB = (const float*)d_in[2];  // [256]
  const float* W1 = (const float*)d_in[3];    // [256 k][256 o] already k-major
  const float* W2 = (const float*)d_in[4];    // [256,256]
  const float* W3 = (const float*)d_in[5];    // [256,64]
  float* out = (float*)d_out;                 // [8192,64]

  float4* xp4 = (float4*)d_ws;                           // 8 MB (also cp)
  float4* rates_p4 = (float4*)((float*)d_ws + 2097152);  // 8 MB
  float* encWT = (float*)d_ws + 4194304;                 // 256 KB

  const float decay = (float)exp((double)(-0.05f));
  const float omd = 1.0f - decay;

  k_transpose256<<<256, 256, 0, stream>>>(encW, encWT);
  k_pack<<<512, 256, 0, stream>>>((const float4*)x, xp4);
  k_gemm_ws<0><<<1024, 256, 0, stream>>>(xp4, encWT, encB, rates_p4, omd);
  // GEMM2 writes cp into xp (xp only read by GEMM1) -> safe aliasing.
  k_gemm_ws<1><<<1024, 256, 0, stream>>>(rates_p4, W1, encB, xp4, omd);
  k_sim<<<2048, 256, 0, stream>>>((const float4*)xp4, W2, W3, out, decay, omd);
}